// Round 1
// 2576.969 us; speedup vs baseline: 1.0021x; 1.0021x over previous
//
#include <hip/hip_runtime.h>
#include <stdint.h>

#define XW 6432

typedef unsigned short u16;
typedef __attribute__((ext_vector_type(8))) __bf16 bf16x8;
typedef __attribute__((ext_vector_type(8))) unsigned short us8;
typedef __attribute__((ext_vector_type(4))) float f32x4;

__device__ __forceinline__ u16 f2bf(float x){
  unsigned u = __builtin_bit_cast(unsigned, x);
  u = (u + 0x7FFFu + ((u >> 16) & 1u)) >> 16;
  return (u16)u;
}
__device__ __forceinline__ float bf2f(u16 h){
  unsigned u = ((unsigned)h) << 16;
  return __builtin_bit_cast(float, u);
}
__device__ __forceinline__ void split2(float x, u16 &hi, u16 &lo){
  hi = f2bf(x);
  lo = f2bf(x - bf2f(hi));
}

// ---------------------------------------------------------------------------
// Split-K GEMM: C_part[split] (256 x N) = A(256 x K) @ W(N x K)^T
// A given as bf16 hi/lo pair (row-major, leading dim lda, zero-padded to a
// multiple of 32 cols). W is fp32 (N x K row-major), converted to bf16 hi/lo
// tiles in LDS. 3-pass split MFMA: Ah*Wh + Ah*Wl + Al*Wh, fp32 accumulate.
// grid = (N/64, KS), block = 256 (4 waves). Wave w: rows 64w..64w+63.
//
// Pipelined version:
//  - A fragments loaded DIRECTLY from global (L2-resident) in MFMA fragment
//    layout — no LDS round-trip for A (same L2 bytes / 64B transactions).
//  - W tile staged via LDS (must be shared across waves; HBM-unique read),
//    double-buffered, ONE raw s_barrier per step preceded by lgkmcnt(0) only
//    (no vmcnt drain — prefetch loads stay in flight across the barrier).
//  - Depth-1 register prefetch: step s+1 loads (W issued first, then A)
//    fly under step s's MFMA phase.
// ---------------------------------------------------------------------------
struct APref { us8 h[4]; us8 l[4]; };
struct WPref { float4 w0, w1; };

__launch_bounds__(256)
__global__ void k_gemm(const u16* __restrict__ Ahi, const u16* __restrict__ Alo, int lda,
                       const float* __restrict__ W, int N, int K, int kchunk,
                       float* __restrict__ Cpart)
{
  __shared__ u16 sWh[2][64*40];   // row stride 40 (80B): 2-way banks only
  __shared__ u16 sWl[2][64*40];

  const int tid  = threadIdx.x;
  const int wid  = tid >> 6;
  const int lane = tid & 63;
  const int n0   = blockIdx.x * 64;
  const int k0   = blockIdx.y * kchunk;
  const int k1   = (k0 + kchunk < K) ? (k0 + kchunk) : K;
  const int nsteps = (k1 - k0 + 31) >> 5;

  const int sr = tid >> 2;        // W staging row 0..63
  const int sc = (tid & 3) * 8;   // W staging col offset (elements)

  const int colrow = lane & 15;
  const int koff   = (lane >> 4) * 8;

  f32x4 acc[4][4];
  #pragma unroll
  for (int i=0;i<4;++i)
    #pragma unroll
    for (int j=0;j<4;++j)
      acc[i][j] = f32x4{0.f,0.f,0.f,0.f};

  // A fragment base: row = wid*64 + mi*16 + colrow, col = kb + koff
  const u16* Abase_h = Ahi + (size_t)(wid*64 + colrow) * lda + koff;
  const u16* Abase_l = Alo + (size_t)(wid*64 + colrow) * lda + koff;
  const float* wrow  = W + (size_t)(n0 + sr) * K;

  auto loadW = [&](WPref& d, int kb){
    if (kb + 32 <= K){
      d.w0 = *(const float4*)(wrow + kb + sc);
      d.w1 = *(const float4*)(wrow + kb + sc + 4);
    } else {
      float t[8];
      #pragma unroll
      for (int jj=0;jj<8;++jj){
        const int k = kb + sc + jj;
        t[jj] = (k < K) ? wrow[k] : 0.f;
      }
      d.w0 = float4{t[0],t[1],t[2],t[3]};
      d.w1 = float4{t[4],t[5],t[6],t[7]};
    }
  };
  auto loadA = [&](APref& d, int kb){
    #pragma unroll
    for (int mi=0;mi<4;++mi){
      d.h[mi] = *(const us8*)(Abase_h + (size_t)(mi*16)*lda + kb);
      d.l[mi] = *(const us8*)(Abase_l + (size_t)(mi*16)*lda + kb);
    }
  };

  auto step = [&](const APref& cA, const WPref& cW, APref& nA, WPref& nW,
                  int kbn, bool doload, int par){
    // convert current W prefetch regs -> bf16 hi/lo (VALU; overlaps MFMA tail
    // of the previous step via separate pipes)
    us8 vh, vl;
    {
      float v[8] = {cW.w0.x, cW.w0.y, cW.w0.z, cW.w0.w,
                    cW.w1.x, cW.w1.y, cW.w1.z, cW.w1.w};
      #pragma unroll
      for (int jj=0;jj<8;++jj){ u16 h,l; split2(v[jj],h,l); vh[jj]=h; vl[jj]=l; }
    }
    *(us8*)&sWh[par][sr*40 + sc] = vh;
    *(us8*)&sWl[par][sr*40 + sc] = vl;
    // issue next-step loads (W first so the next convert waits vmcnt(8), not 0)
    if (doload){ loadW(nW, kbn); loadA(nA, kbn); }
    // drain only LDS writes; prefetch vmem stays in flight across the barrier
    asm volatile("s_waitcnt lgkmcnt(0)" ::: "memory");
    __builtin_amdgcn_s_barrier();
    asm volatile("" ::: "memory");
    // B fragments from LDS
    bf16x8 bh[4], bl[4];
    #pragma unroll
    for (int ni=0;ni<4;++ni){
      const int r = ni*16 + colrow;
      bh[ni] = *(const bf16x8*)&sWh[par][r*40 + koff];
      bl[ni] = *(const bf16x8*)&sWl[par][r*40 + koff];
    }
    #pragma unroll
    for (int mi=0;mi<4;++mi){
      const bf16x8 ah = __builtin_bit_cast(bf16x8, cA.h[mi]);
      const bf16x8 al = __builtin_bit_cast(bf16x8, cA.l[mi]);
      #pragma unroll
      for (int ni=0;ni<4;++ni){
        acc[mi][ni] = __builtin_amdgcn_mfma_f32_16x16x32_bf16(ah, bh[ni], acc[mi][ni], 0,0,0);
        acc[mi][ni] = __builtin_amdgcn_mfma_f32_16x16x32_bf16(ah, bl[ni], acc[mi][ni], 0,0,0);
        acc[mi][ni] = __builtin_amdgcn_mfma_f32_16x16x32_bf16(al, bh[ni], acc[mi][ni], 0,0,0);
      }
    }
  };

  APref a0, a1; WPref w0, w1;
  loadW(w0, k0); loadA(a0, k0);           // prologue: tile 0 in flight
  int s = 0;
  for (; s + 2 <= nsteps; s += 2){
    step(a0, w0, a1, w1, k0 + (s+1)*32, true, 0);
    step(a1, w1, a0, w0, k0 + (s+2)*32, (s+2) < nsteps, 1);
  }
  if (s < nsteps)
    step(a0, w0, a1, w1, 0, false, 0);    // odd tail (parity 0; prev was 1)

  // ---- write fp32 partials. C/D layout: col=lane&15, row=(lane>>4)*4+reg ----
  float* outp = Cpart + (size_t)blockIdx.y * 256 * N;
  const int rq = (lane >> 4) * 4;
  #pragma unroll
  for (int mi=0;mi<4;++mi){
    const int rowb = wid*64 + mi*16 + rq;
    #pragma unroll
    for (int ni=0;ni<4;++ni){
      const int col = n0 + ni*16 + colrow;
      #pragma unroll
      for (int r=0;r<4;++r)
        outp[(size_t)(rowb + r) * N + col] = acc[mi][ni][r];
    }
  }
}

// ---------------------------------------------------------------------------
// prep0: d split, q = pi/4 d^2 (+split), s split.  grid 4096 x 256thr
// ---------------------------------------------------------------------------
__global__ void k_prep0(const float* __restrict__ x,
                        u16* __restrict__ dhi, u16* __restrict__ dlo,
                        float* __restrict__ q, u16* __restrict__ qhi, u16* __restrict__ qlo,
                        u16* __restrict__ shi, u16* __restrict__ slo)
{
  const int idx = blockIdx.x*256 + threadIdx.x;     // 256*4096
  const int m = idx >> 12, j = idx & 4095;
  const float d = x[(size_t)m*XW + 96 + j];
  u16 h,l;
  split2(d,h,l); dhi[idx]=h; dlo[idx]=l;
  const float qq = 0.78539816339744830962f * d * d;
  q[idx]=qq; split2(qq,h,l); qhi[idx]=h; qlo[idx]=l;
  if (j < 2048){
    const float sv = x[(size_t)m*XW + 4192 + j];
    split2(sv,h,l);
    const int si = m*2048+j; shi[si]=h; slo[si]=l;
  }
}

// ---------------------------------------------------------------------------
// h0 GEMMs (K=96, fp32 VALU): res_h0_q (N=4096), res_h0_h (N=2112)
// grid (97, 16) x 64thr, each block: 64 cols x 16 batch rows
// ---------------------------------------------------------------------------
__global__ void k_h0(const float* __restrict__ x,
                     const float* __restrict__ Wq, const float* __restrict__ bq,
                     const float* __restrict__ Wh, const float* __restrict__ bh,
                     float* __restrict__ rhq, float* __restrict__ rhh)
{
  __shared__ float xr[16][96];
  const int t = threadIdx.x;
  const int m0 = blockIdx.y * 16;
  for (int i=t; i<16*96; i+=64){
    const int mm=i/96, k=i%96;
    xr[mm][k] = x[(size_t)(m0+mm)*XW + k];
  }
  __syncthreads();
  const int n = blockIdx.x*64 + t;   // 0..6207
  float acc[16];
  if (n < 4096){
    const float* w = Wq + (size_t)n*96;
    const float b = bq[n];
    #pragma unroll
    for (int mm=0;mm<16;++mm) acc[mm]=b;
    for (int k=0;k<96;++k){
      const float wv = w[k];
      #pragma unroll
      for (int mm=0;mm<16;++mm) acc[mm] += xr[mm][k]*wv;
    }
    #pragma unroll
    for (int mm=0;mm<16;++mm) rhq[(size_t)(m0+mm)*4096 + n] = acc[mm];
  } else {
    const int nn = n - 4096;
    const float* w = Wh + (size_t)nn*96;
    const float b = bh[nn];
    #pragma unroll
    for (int mm=0;mm<16;++mm) acc[mm]=b;
    for (int k=0;k<96;++k){
      const float wv = w[k];
      #pragma unroll
      for (int mm=0;mm<16;++mm) acc[mm] += xr[mm][k]*wv;
    }
    #pragma unroll
    for (int mm=0;mm<16;++mm) rhh[(size_t)(m0+mm)*2112 + nn] = acc[mm];
  }
}

// ---------------------------------------------------------------------------
// cPre: finalize res_S_q / res_q_h / res_s_q; build rsum_q, rh, A1.  grid 4128
// ---------------------------------------------------------------------------
__global__ void k_cpre(const float* __restrict__ P0, const float* __restrict__ P1,
                       const float* __restrict__ P2,
                       const float* __restrict__ bS, const float* __restrict__ bq0h,
                       const float* __restrict__ bsq,
                       const float* __restrict__ rhq, const float* __restrict__ rhh,
                       const float* __restrict__ q, const float* __restrict__ x,
                       float* __restrict__ resS, float* __restrict__ rsumq,
                       float* __restrict__ rh,
                       u16* __restrict__ A1hi, u16* __restrict__ A1lo)
{
  const int idx = blockIdx.x*256 + threadIdx.x;    // 256*4128
  const int m = idx / 4128, j = idx % 4128;
  if (j < 2112){
    float v = bq0h[j];
    #pragma unroll
    for (int s=0;s<8;++s) v += P1[(size_t)s*540672 + m*2112 + j];
    rh[m*2112+j] = rhh[m*2112+j] + v;               // res_h0_h + res_q_h (no relu)
  }
  u16 h,l;
  if (j < 4096){
    const int ij = m*4096 + j;
    float vS = bS[j];
    #pragma unroll
    for (int s=0;s<4;++s) vS += P0[(size_t)s*1048576 + ij];
    vS = vS > 0.f ? vS : 0.f;                        // relu
    resS[ij] = vS;
    float vq = bsq[j];
    #pragma unroll
    for (int s=0;s<4;++s) vq += P2[(size_t)s*1048576 + ij];
    rsumq[ij] = vq + rhq[ij];                        // res_s_q + res_h0_q
    const float a1 = q[ij]*vS;
    split2(a1,h,l); A1hi[m*4128+j]=h; A1lo[m*4128+j]=l;
  } else if (j < 4104){
    const float a1 = x[(size_t)m*XW + 6240 + (j-4096)];  // pump settings
    split2(a1,h,l); A1hi[m*4128+j]=h; A1lo[m*4128+j]=l;
  } else {
    A1hi[m*4128+j]=0; A1lo[m*4128+j]=0;              // pad to K-multiple-of-32
  }
}

// cD: D_q = b + sum P0; split D_q; A2 = D_q*(q+rsum_q). grid 4096
__global__ void k_cd(const float* __restrict__ P0, const float* __restrict__ bDq,
                     const float* __restrict__ q, const float* __restrict__ rsumq,
                     u16* __restrict__ Dqhi, u16* __restrict__ Dqlo,
                     u16* __restrict__ A2hi, u16* __restrict__ A2lo)
{
  const int idx = blockIdx.x*256 + threadIdx.x;     // 256*4096
  const int j = idx & 4095;
  float v = bDq[j];
  #pragma unroll
  for (int s=0;s<4;++s) v += P0[(size_t)s*1048576 + idx];
  u16 h,l;
  split2(v,h,l); Dqhi[idx]=h; Dqlo[idx]=l;
  const float a2 = v * (q[idx] + rsumq[idx]);
  split2(a2,h,l); A2hi[idx]=h; A2lo[idx]=l;
}

// cH: D_h = relu(..P1), hfh = relu(..P2); A3 = (h + rh)*D_h.  grid 2112
__global__ void k_ch(const float* __restrict__ P1, const float* __restrict__ P2,
                     const float* __restrict__ bDh, const float* __restrict__ bfh,
                     const float* __restrict__ rh,
                     u16* __restrict__ A3hi, u16* __restrict__ A3lo)
{
  const int idx = blockIdx.x*256 + threadIdx.x;     // 256*2112
  const int j = idx % 2112;
  float dh = bDh[j], hh = bfh[j];
  #pragma unroll
  for (int s=0;s<8;++s){
    dh += P1[(size_t)s*540672 + idx];
    hh += P2[(size_t)s*540672 + idx];
  }
  dh = dh > 0.f ? dh : 0.f;
  hh = hh > 0.f ? hh : 0.f;
  const float a3 = (hh + rh[idx]) * dh;
  u16 h,l; split2(a3,h,l); A3hi[idx]=h; A3lo[idx]=l;
}

// cQ: t = b + sum P0; q -= prelu(t); split q; A1 = q*res_S_q.  grid 4096
__global__ void k_cq(const float* __restrict__ P0, const float* __restrict__ bhf,
                     const float* __restrict__ prelu_a, int bi,
                     float* __restrict__ q, const float* __restrict__ resS,
                     u16* __restrict__ qhi, u16* __restrict__ qlo,
                     u16* __restrict__ A1hi, u16* __restrict__ A1lo)
{
  const int idx = blockIdx.x*256 + threadIdx.x;     // 256*4096
  const int m = idx >> 12, j = idx & 4095;
  float t = bhf[j];
  #pragma unroll
  for (int s=0;s<4;++s) t += P0[(size_t)s*1048576 + idx];
  const float a = prelu_a[bi];
  const float hid = (t >= 0.f) ? t : a*t;
  const float qn = q[idx] - hid;
  q[idx] = qn;
  u16 h,l;
  split2(qn,h,l); qhi[idx]=h; qlo[idx]=l;
  const float a1 = qn * resS[idx];
  split2(a1,h,l); A1hi[m*4128+j]=h; A1lo[m*4128+j]=l;
}

// cR: rh = res_h0_h + relu(b + sum P1).  grid 2112
__global__ void k_cr(const float* __restrict__ P1, const float* __restrict__ bresq,
                     const float* __restrict__ rhh, float* __restrict__ rh)
{
  const int idx = blockIdx.x*256 + threadIdx.x;     // 256*2112
  const int j = idx % 2112;
  float v = bresq[j];
  #pragma unroll
  for (int s=0;s<8;++s) v += P1[(size_t)s*540672 + idx];
  v = v > 0.f ? v : 0.f;
  rh[idx] = rhh[idx] + v;
}

// cOut: out = b + sum P1.  grid 2112
__global__ void k_cout(const float* __restrict__ P1, const float* __restrict__ bout,
                       float* __restrict__ outp)
{
  const int idx = blockIdx.x*256 + threadIdx.x;     // 256*2112
  const int j = idx % 2112;
  float v = bout[j];
  #pragma unroll
  for (int s=0;s<8;++s) v += P1[(size_t)s*540672 + idx];
  outp[idx] = v;
}

// ---------------------------------------------------------------------------
extern "C" void kernel_launch(void* const* d_in, const int* in_sizes, int n_in,
                              void* d_out, int out_size, void* d_ws, size_t ws_size,
                              hipStream_t stream)
{
  const float* x      = (const float*)d_in[0];
  const float* W_h0_q = (const float*)d_in[2];
  const float* b_h0_q = (const float*)d_in[3];
  const float* W_h0_h = (const float*)d_in[4];
  const float* b_h0_h = (const float*)d_in[5];
  const float* W_S    = (const float*)d_in[6];
  const float* b_S    = (const float*)d_in[7];
  const float* W_q0_h = (const float*)d_in[8];
  const float* b_q0_h = (const float*)d_in[9];
  const float* W_s_q  = (const float*)d_in[10];
  const float* b_s_q  = (const float*)d_in[11];
  const float* W_out  = (const float*)d_in[12];
  const float* b_out  = (const float*)d_in[13];
  const float* W_hf   = (const float*)d_in[14];
  const float* b_hf   = (const float*)d_in[15];
  const float* W_fh   = (const float*)d_in[16];
  const float* b_fh   = (const float*)d_in[17];
  const float* W_resq = (const float*)d_in[18];
  const float* b_resq = (const float*)d_in[19];
  const float* W_Dq   = (const float*)d_in[20];
  const float* b_Dq   = (const float*)d_in[21];
  const float* W_Dh   = (const float*)d_in[22];
  const float* b_Dh   = (const float*)d_in[23];
  const float* prelu_a= (const float*)d_in[24];

  char* ws = (char*)d_ws;
  size_t off = 0;
  auto alloc = [&](size_t n)->char*{ char* p = ws + off; off += (n + 255) & ~(size_t)255; return p; };

  u16* A1hi = (u16*)alloc((size_t)256*4128*2);
  u16* A1lo = (u16*)alloc((size_t)256*4128*2);
  u16* qhi  = (u16*)alloc((size_t)256*4096*2);
  u16* qlo  = (u16*)alloc((size_t)256*4096*2);
  u16* dhi  = (u16*)alloc((size_t)256*4096*2);
  u16* dlo  = (u16*)alloc((size_t)256*4096*2);
  u16* shi  = (u16*)alloc((size_t)256*2048*2);
  u16* slo  = (u16*)alloc((size_t)256*2048*2);
  u16* A2hi = (u16*)alloc((size_t)256*4096*2);
  u16* A2lo = (u16*)alloc((size_t)256*4096*2);
  u16* A3hi = (u16*)alloc((size_t)256*2112*2);
  u16* A3lo = (u16*)alloc((size_t)256*2112*2);
  u16* Dqhi = (u16*)alloc((size_t)256*4096*2);
  u16* Dqlo = (u16*)alloc((size_t)256*4096*2);
  float* q     = (float*)alloc((size_t)256*4096*4);
  float* resS  = (float*)alloc((size_t)256*4096*4);
  float* rsumq = (float*)alloc((size_t)256*4096*4);
  float* rh    = (float*)alloc((size_t)256*2112*4);
  float* rhq   = (float*)alloc((size_t)256*4096*4);
  float* rhh   = (float*)alloc((size_t)256*2112*4);
  float* P0    = (float*)alloc((size_t)4*1048576*4);   // KS=4, N=4096
  float* P1    = (float*)alloc((size_t)8*540672*4);    // KS=8, N=2112
  float* P2    = (float*)alloc((size_t)8*540672*4);    // reused: KS4/N4096 or KS8/N2112

  // ---- pre-loop ----
  k_prep0<<<4096, 256, 0, stream>>>(x, dhi, dlo, q, qhi, qlo, shi, slo);
  k_h0<<<dim3(97,16), 64, 0, stream>>>(x, W_h0_q, b_h0_q, W_h0_h, b_h0_h, rhq, rhh);
  k_gemm<<<dim3(64,4), 256, 0, stream>>>(dhi, dlo, 4096, W_S,    4096, 4096, 1024, P0);
  k_gemm<<<dim3(33,8), 256, 0, stream>>>(qhi, qlo, 4096, W_q0_h, 2112, 4096,  512, P1);
  k_gemm<<<dim3(64,4), 256, 0, stream>>>(shi, slo, 2048, W_s_q,  4096, 2048,  512, P2);
  k_cpre<<<4128, 256, 0, stream>>>(P0, P1, P2, b_S, b_q0_h, b_s_q, rhq, rhh, q, x,
                                   resS, rsumq, rh, A1hi, A1lo);

  // ---- 6 unrolled iterations ----
  for (int i = 0; i < 6; ++i){
    const float* Wdq = W_Dq   + (size_t)i*4096*4104;
    const float* Wdh = W_Dh   + (size_t)i*2112*4096;
    const float* Wfh = W_fh   + (size_t)i*2112*4096;
    const float* Whf = W_hf   + (size_t)i*4096*2112;
    const float* Wrq = W_resq + (size_t)i*2112*4096;

    k_gemm<<<dim3(64,4), 256, 0, stream>>>(A1hi, A1lo, 4128, Wdq, 4096, 4104, 1056, P0);
    k_cd<<<4096, 256, 0, stream>>>(P0, b_Dq + (size_t)i*4096, q, rsumq, Dqhi, Dqlo, A2hi, A2lo);
    k_gemm<<<dim3(33,8), 256, 0, stream>>>(Dqhi, Dqlo, 4096, Wdh, 2112, 4096, 512, P1);
    k_gemm<<<dim3(33,8), 256, 0, stream>>>(A2hi, A2lo, 4096, Wfh, 2112, 4096, 512, P2);
    k_ch<<<2112, 256, 0, stream>>>(P1, P2, b_Dh + (size_t)i*2112, b_fh + (size_t)i*2112, rh, A3hi, A3lo);
    k_gemm<<<dim3(64,4), 256, 0, stream>>>(A3hi, A3lo, 2112, Whf, 4096, 2112, 544, P0);
    k_cq<<<4096, 256, 0, stream>>>(P0, b_hf + (size_t)i*4096, prelu_a, i, q, resS, qhi, qlo, A1hi, A1lo);
    k_gemm<<<dim3(33,8), 256, 0, stream>>>(qhi, qlo, 4096, Wrq, 2112, 4096, 512, P1);
    k_cr<<<2112, 256, 0, stream>>>(P1, b_resq + (size_t)i*2112, rhh, rh);
  }

  // ---- output ----
  k_gemm<<<dim3(33,8), 256, 0, stream>>>(qhi, qlo, 4096, W_out, 2112, 4096, 512, P1);
  k_cout<<<2112, 256, 0, stream>>>(P1, b_out, (float*)d_out);
}